// Round 3
// baseline (272.295 us; speedup 1.0000x reference)
//
#include <hip/hip_runtime.h>
#include <math.h>

typedef __attribute__((ext_vector_type(8))) short bh8;    // 8 bf16 in 4 VGPRs
typedef __attribute__((ext_vector_type(4))) float f32x4;  // MFMA accumulator
typedef __attribute__((ext_vector_type(2))) unsigned u32x2;

namespace {
constexpr int Bn = 4, Tn = 2048, Cn = 1024, Hn = 16, Dn = 64, INNERn = 1024, OUTn = 1024;
constexpr int Mn = Bn * Tn;  // 8192 tokens
}

// async 16B global->LDS (wave-uniform base + lane*16 placement)
__device__ __forceinline__ void glds16(const void* g, void* l) {
    __builtin_amdgcn_global_load_lds(
        (const __attribute__((address_space(1))) void*)g,
        (__attribute__((address_space(3))) void*)l, 16, 0, 0);
}

// waitcnt vmcnt(0) lgkmcnt(0) + barrier — prefetch-friendly (loads issued at
// iter top are a full body old by the time we wait).
__device__ __forceinline__ void barrier_vm0() {
    __builtin_amdgcn_s_waitcnt(0x0070);
    __builtin_amdgcn_s_barrier();
}

// fp32 -> bf16 round-to-nearest-even
__device__ __forceinline__ ushort f2bf(float f) {
    union { float f; unsigned u; } v; v.f = f;
    unsigned r = v.u + 0x7fffu + ((v.u >> 16) & 1u);
    return (ushort)(r >> 16);
}
__device__ __forceinline__ unsigned pack_rne(float a, float b) {
    return (unsigned)f2bf(a) | ((unsigned)f2bf(b) << 16);
}
// truncation-pack: low16 = trunc(a), high16 = trunc(b)  (1 VALU op)
__device__ __forceinline__ unsigned pack_trunc(float a, float b) {
    return __builtin_amdgcn_perm(__float_as_uint(a), __float_as_uint(b), 0x03020706u);
}

// one launch: x (8192 blocks) + 4 weights (1024 blocks each)
__global__ __launch_bounds__(256)
void cvt_all(const float* __restrict__ x,  const float* __restrict__ Wk,
             const float* __restrict__ Wq, const float* __restrict__ Wv,
             const float* __restrict__ Wp,
             ushort* __restrict__ xb,  ushort* __restrict__ wkb,
             ushort* __restrict__ wqb, ushort* __restrict__ wvb,
             ushort* __restrict__ wpb)
{
    const int bid = blockIdx.x;
    const float* s; ushort* d; float sc; int i;
    if (bid < 8192) {
        s = x; d = xb; sc = 0.03125f;             // fold C^-0.5 (exact pow2)
        i = bid * 256 + threadIdx.x;
    } else {
        const int seg = (bid - 8192) >> 10;
        i = ((bid - 8192) & 1023) * 256 + threadIdx.x;
        s  = (seg == 0) ? Wk : (seg == 1) ? Wq : (seg == 2) ? Wv : Wp;
        d  = (seg == 0) ? wkb : (seg == 1) ? wqb : (seg == 2) ? wvb : wpb;
        sc = (seg == 3) ? 0.03125f : 1.0f;        // fold INNER^-0.5 into Wp
    }
    float4 f = ((const float4*)s)[i];
    ushort4 o;
    o.x = f2bf(f.x * sc); o.y = f2bf(f.y * sc);
    o.z = f2bf(f.z * sc); o.w = f2bf(f.w * sc);
    ((ushort4*)d)[i] = o;
}

// ---------------------------------------------------------------------------
// Fused QKV projection GEMM (128x128 tile, BK=32, dbuf, single vm0-barrier
// per K-iter). Q/K out: bf16 [B,H,T,D]; V out: bf16 [B,H,D,T] via LDS-staged
// coalesced stores. 1-D grid with XCD-grouped decode: blocks sharing an
// A-panel (same m-tile) land on the same XCD so the 256KB panel stays
// L2-resident across its 24 consumer blocks.
// ---------------------------------------------------------------------------
__global__ __launch_bounds__(256)
void gemm_qkv(const ushort* __restrict__ A, const ushort* __restrict__ Wq,
              const ushort* __restrict__ Wk, const ushort* __restrict__ Wv,
              ushort* __restrict__ Oq, ushort* __restrict__ Ok,
              ushort* __restrict__ Ovt, float qscale)
{
    __shared__ char SM[32768];     // As[2] | Bs[2]; reused for V^T epilogue
    char* As0 = SM;          char* As1 = SM + 8192;
    char* Bs0 = SM + 16384;  char* Bs1 = SM + 24576;
    const int tid = threadIdx.x;
    const int w = tid >> 6, lane = tid & 63, quad = lane >> 4, l = lane & 15;
    // XCD-grouped: 1536 blocks; xcd = lid&7; 8 m-panels per XCD x 24 n-blocks
    const int lid = blockIdx.x;
    const int xcd = lid & 7, j = lid >> 3;         // j in 0..191
    const int ytile = xcd * 8 + j / 24;            // m-tile 0..63
    const int xx = j % 24;                         // 0..23
    const int sel = xx >> 3;
    const ushort* Bw = (sel == 0) ? Wq : (sel == 1) ? Wk : Wv;
    const int n0 = (xx & 7) * 128, m0 = ytile * 128;
    const int wm = w >> 1, wn = w & 1;

    auto stage = [&](char* Ad, char* Bd, int k0) {
#pragma unroll
        for (int rr = 0; rr < 2; ++rr) {
            const int rho = w * 2 + rr;
            const int row = rho * 16 + (lane >> 2);
            const int kq  = (lane & 3) * 8;
            glds16(A  + (size_t)(m0 + row) * Cn + k0 + kq, Ad + rho * 1024 + lane * 16);
            glds16(Bw + (size_t)(n0 + row) * Cn + k0 + kq, Bd + rho * 1024 + lane * 16);
        }
    };

    f32x4 acc[4][4];
#pragma unroll
    for (int i = 0; i < 4; ++i)
#pragma unroll
        for (int j2 = 0; j2 < 4; ++j2) acc[i][j2] = (f32x4){0.f, 0.f, 0.f, 0.f};

    stage(As0, Bs0, 0);
    barrier_vm0();
#pragma unroll 2
    for (int it = 0; it < 32; ++it) {
        const int cur = it & 1;
        if (it < 31) stage(cur ? As0 : As1, cur ? Bs0 : Bs1, (it + 1) * 32);
        const char* Ac = cur ? As1 : As0; const char* Bc = cur ? Bs1 : Bs0;
        bh8 af[4], bf[4];
#pragma unroll
        for (int mf = 0; mf < 4; ++mf)
            af[mf] = *(const bh8*)(Ac + (wm * 64 + mf * 16 + l) * 64 + quad * 16);
#pragma unroll
        for (int nf = 0; nf < 4; ++nf)
            bf[nf] = *(const bh8*)(Bc + (wn * 64 + nf * 16 + l) * 64 + quad * 16);
#pragma unroll
        for (int mf = 0; mf < 4; ++mf)
#pragma unroll
            for (int nf = 0; nf < 4; ++nf)
                acc[mf][nf] = __builtin_amdgcn_mfma_f32_16x16x32_bf16(af[mf], bf[nf], acc[mf][nf], 0, 0, 0);
        barrier_vm0();
    }

    // epilogue: C/D layout col = l, row = quad*4 + reg
    if (sel < 2) {
        ushort* dU = (sel == 0) ? Oq : Ok;
        const float scale = (sel == 0) ? qscale : 1.0f;
#pragma unroll
        for (int mf = 0; mf < 4; ++mf)
#pragma unroll
            for (int nf = 0; nf < 4; ++nf) {
                const int mb = m0 + wm * 64 + mf * 16 + quad * 4;
                const int n  = n0 + wn * 64 + nf * 16 + l;
                const int h = n >> 6, dd = n & 63;
#pragma unroll
                for (int reg = 0; reg < 4; ++reg) {
                    const int m = mb + reg;
                    const int b = m >> 11, t = m & (Tn - 1);
                    dU[((size_t)(b * Hn + h) * Tn + t) * Dn + dd] = f2bf(acc[mf][nf][reg] * scale);
                }
            }
    } else {
        // V^T: stash tile [n][m] bf16 in LDS (XOR-swizzled 16B chunks), then
        // coalesced 256B-run stores into [B,H,D,T].
#pragma unroll
        for (int mf = 0; mf < 4; ++mf)
#pragma unroll
            for (int nf = 0; nf < 4; ++nf) {
                const int mb = wm * 64 + mf * 16 + quad * 4;   // tile-local m
                const int n  = wn * 64 + nf * 16 + l;          // tile-local n
                uint2 p;
                p.x = pack_rne(acc[mf][nf][0], acc[mf][nf][1]);
                p.y = pack_rne(acc[mf][nf][2], acc[mf][nf][3]);
                const int c = mb >> 3;                         // 16B chunk of m
                *(uint2*)(SM + n * 256 + ((c ^ (n & 15)) & 15) * 16 + (mb & 7) * 2) = p;
            }
        __syncthreads();
        const int bb = m0 >> 11, t0 = m0 & (Tn - 1);
#pragma unroll
        for (int it2 = 0; it2 < 8; ++it2) {
            const int n = it2 * 16 + w * 4 + quad;             // tile-local n
            const int ng = n0 + n;
            const int h = ng >> 6, dd = ng & 63;
            int4 vsm = *(const int4*)(SM + n * 256 + ((l ^ (n & 15)) & 15) * 16);
            *(int4*)(Ovt + ((size_t)(bb * Hn + h) * Dn + dd) * Tn + t0 + l * 8) = vsm;
        }
    }
}

// ---------------------------------------------------------------------------
// Output projection: out = ao(8192x1024) * Wp(1024x1024)^T, fp32 out.
// XCD-grouped 1-D grid: same-m-panel blocks co-XCD.
// ---------------------------------------------------------------------------
__global__ __launch_bounds__(256)
void gemm_po(const ushort* __restrict__ A, const ushort* __restrict__ Bw,
             float* __restrict__ Cout)
{
    __shared__ char As[2][8192];
    __shared__ char Bs[2][8192];
    const int tid = threadIdx.x;
    const int w = tid >> 6, lane = tid & 63, quad = lane >> 4, l = lane & 15;
    // 512 blocks: xcd = lid&7; 8 m-panels per XCD x 8 n-blocks
    const int lid = blockIdx.x;
    const int xcd = lid & 7, j = lid >> 3;         // j in 0..63
    const int n0 = (j & 7) * 128, m0 = (xcd * 8 + (j >> 3)) * 128;
    const int wm = w >> 1, wn = w & 1;

    auto stage = [&](int bsel, int k0) {
#pragma unroll
        for (int rr = 0; rr < 2; ++rr) {
            const int rho = w * 2 + rr;
            const int row = rho * 16 + (lane >> 2);
            const int kq  = (lane & 3) * 8;
            glds16(A  + (size_t)(m0 + row) * Cn + k0 + kq, As[bsel] + rho * 1024 + lane * 16);
            glds16(Bw + (size_t)(n0 + row) * Cn + k0 + kq, Bs[bsel] + rho * 1024 + lane * 16);
        }
    };

    f32x4 acc[4][4];
#pragma unroll
    for (int i = 0; i < 4; ++i)
#pragma unroll
        for (int j2 = 0; j2 < 4; ++j2) acc[i][j2] = (f32x4){0.f, 0.f, 0.f, 0.f};

    stage(0, 0);
    barrier_vm0();
#pragma unroll 2
    for (int it = 0; it < 32; ++it) {
        const int cur = it & 1;
        if (it < 31) stage(cur ^ 1, (it + 1) * 32);
        const char* Ac = As[cur]; const char* Bc = Bs[cur];
        bh8 af[4], bf[4];
#pragma unroll
        for (int mf = 0; mf < 4; ++mf)
            af[mf] = *(const bh8*)(Ac + (wm * 64 + mf * 16 + l) * 64 + quad * 16);
#pragma unroll
        for (int nf = 0; nf < 4; ++nf)
            bf[nf] = *(const bh8*)(Bc + (wn * 64 + nf * 16 + l) * 64 + quad * 16);
#pragma unroll
        for (int mf = 0; mf < 4; ++mf)
#pragma unroll
            for (int nf = 0; nf < 4; ++nf)
                acc[mf][nf] = __builtin_amdgcn_mfma_f32_16x16x32_bf16(af[mf], bf[nf], acc[mf][nf], 0, 0, 0);
        barrier_vm0();
    }

#pragma unroll
    for (int mf = 0; mf < 4; ++mf)
#pragma unroll
        for (int nf = 0; nf < 4; ++nf) {
            const int mb = m0 + wm * 64 + mf * 16 + quad * 4;
            const int n  = n0 + wn * 64 + nf * 16 + l;
#pragma unroll
            for (int reg = 0; reg < 4; ++reg)
                Cout[(size_t)(mb + reg) * OUTn + n] = acc[mf][nf][reg];
        }
}

// ---------------------------------------------------------------------------
// MFMA flash attention v7 = v6 + QBLK 128->64 (occupancy 4->5 blocks/CU,
// 2048 blocks, halved per-wave chains) + XCD-grouped bh decode (all 32
// q-tiles of one (b,h) on one XCD -> 512KB K/V stays L2-resident) +
// s_setprio(1) around MFMA clusters (T5; waves now phase-diverse).
// Per wave: 16 q rows. In-register P transpose via permlane32/16_swap.
// K/V double-buffered (glds prefetch + single vm0-barrier per iter).
// LDS 32KB -> 5 blocks/CU (160KB), 20 waves/CU.
// ---------------------------------------------------------------------------
__global__ __launch_bounds__(256, 4)
void attn_mfma(const ushort* __restrict__ Qg, const ushort* __restrict__ Kg,
               const ushort* __restrict__ Vtg, ushort* __restrict__ Og)
{
    __shared__ char KT[2][8192];  // (r,d): r*128 + (((d>>3) ^ (r&7))<<4) + (d&7)*2
    __shared__ char VT[2][8192];  // (c,d): d*128 + ((c>>3)^(d&7))*16 + (c&7)*2

    const int tid = threadIdx.x;
    const int w = tid >> 6, lane = tid & 63, quad = lane >> 4, l = lane & 15;
    // XCD-grouped decode: 2048 blocks; xcd = lid&7; 8 bh per XCD x 32 q-tiles
    const int lid = blockIdx.x;
    const int xcd = lid & 7, j = lid >> 3;         // j in 0..255
    const int bh = (xcd << 3) | (j >> 5);          // 0..63
    const int q0 = (j & 31) * 64;
    const int b = bh >> 4, h = bh & 15;
    const ushort* Qp = Qg  + (size_t)bh * Tn * Dn;
    const ushort* Kp = Kg  + (size_t)bh * Tn * Dn;
    const ushort* Vp = Vtg + (size_t)bh * Dn * Tn;   // [d][t]

    auto stageK = [&](char* buf, int kt) {
#pragma unroll
        for (int rr = 0; rr < 2; ++rr) {
            const int rho = w * 2 + rr;                    // 0..7, 8 rows each
            const int r8  = lane >> 3;                     // row within block
            const int r   = rho * 8 + r8;                  // key row 0..63
            const int dc  = (lane & 7) ^ r8;               // pre-swizzled chunk
            glds16(Kp + (size_t)(kt * 64 + r) * Dn + dc * 8, buf + rho * 1024 + lane * 16);
        }
    };
    auto stageV = [&](char* buf, int kt) {
#pragma unroll
        for (int rr = 0; rr < 2; ++rr) {
            const int rho = w * 2 + rr;
            const int d = rho * 8 + (lane >> 3);           // 0..63
            const int csrc = (lane & 7) ^ ((lane >> 3) & 7);
            glds16(Vp + (size_t)d * Tn + kt * 64 + csrc * 8, buf + rho * 1024 + lane * 16);
        }
    };

    // ---- Q frags direct from global (B-operand layout; once per block) ----
    bh8 qf[2];
#pragma unroll
    for (int ks = 0; ks < 2; ++ks)
        qf[ks] = *(const bh8*)(Qp + (size_t)(q0 + w * 16 + l) * Dn + ks * 32 + quad * 8);

    bh8 ones;
#pragma unroll
    for (int i = 0; i < 8; ++i) ones[i] = (short)0x3F80;   // bf16 1.0

    f32x4 oacc[4], lacc;
    lacc = (f32x4){0.f, 0.f, 0.f, 0.f};
#pragma unroll
    for (int dt = 0; dt < 4; ++dt) oacc[dt] = (f32x4){0.f, 0.f, 0.f, 0.f};

    const f32x4 zero = (f32x4){0.f, 0.f, 0.f, 0.f};

    stageK(KT[0], 0);
    stageV(VT[0], 0);
    barrier_vm0();

#pragma unroll 2
    for (int kt = 0; kt < Tn / 64; ++kt) {
        const int cur = kt & 1;
        if (kt < Tn / 64 - 1) {           // prefetch next tile (in flight all body)
            stageK(KT[cur ^ 1], kt + 1);
            stageV(VT[cur ^ 1], kt + 1);
        }
        const char* Kc = KT[cur];
        const char* Vc = VT[cur];

        // ---- two 32-key halves: S -> exp -> in-reg transpose -> PV ----
#pragma unroll
        for (int hh = 0; hh < 2; ++hh) {
            // K frags for keys hh*32..+31 (A-operand: m=key, k=d)
            // KT read with the same XOR the staging applied: row&7 == l&7.
            bh8 kf[2][2];
#pragma unroll
            for (int k8l = 0; k8l < 2; ++k8l) {
                const int row = (hh * 2 + k8l) * 16 + l;
#pragma unroll
                for (int ks = 0; ks < 2; ++ks)
                    kf[k8l][ks] = *(const bh8*)(Kc + row * 128 + (((ks * 4 + quad) ^ (l & 7)) * 16));
            }

            // S^T = K Q^T : rows=keys(quad*4+reg), col=q(l)
            f32x4 st[2];
            __builtin_amdgcn_s_setprio(1);
#pragma unroll
            for (int k8l = 0; k8l < 2; ++k8l) {
                st[k8l] = __builtin_amdgcn_mfma_f32_16x16x32_bf16(kf[k8l][0], qf[0], zero, 0, 0, 0);
                st[k8l] = __builtin_amdgcn_mfma_f32_16x16x32_bf16(kf[k8l][1], qf[1], st[k8l], 0, 0, 0);
            }
            __builtin_amdgcn_s_setprio(0);

            // P = exp2(S) -> trunc-bf16 pairs -> permlane transpose to
            // B-operand layout (keys quad*8+j, q=l), all in registers.
            const unsigned a0 = pack_trunc(__builtin_amdgcn_exp2f(st[0][0]),
                                           __builtin_amdgcn_exp2f(st[0][1]));
            const unsigned a1 = pack_trunc(__builtin_amdgcn_exp2f(st[0][2]),
                                           __builtin_amdgcn_exp2f(st[0][3]));
            const unsigned b0 = pack_trunc(__builtin_amdgcn_exp2f(st[1][0]),
                                           __builtin_amdgcn_exp2f(st[1][1]));
            const unsigned b1 = pack_trunc(__builtin_amdgcn_exp2f(st[1][2]),
                                           __builtin_amdgcn_exp2f(st[1][3]));
            const u32x2 p = __builtin_amdgcn_permlane32_swap(a0, b0, false, false);
            const u32x2 q = __builtin_amdgcn_permlane16_swap(p.x, p.y, false, false);
            const u32x2 r = __builtin_amdgcn_permlane32_swap(a1, b1, false, false);
            const u32x2 s = __builtin_amdgcn_permlane16_swap(r.x, r.y, false, false);
            union { unsigned u[4]; bh8 v; } pu;
            pu.u[0] = q.x; pu.u[1] = s.x; pu.u[2] = q.y; pu.u[3] = s.y;
            const bh8 pf = pu.v;

            // O += P V ; l += ones*P (B-operand pf: n=q, k=keys of half)
            bh8 vf[4];
#pragma unroll
            for (int dt = 0; dt < 4; ++dt)
                vf[dt] = *(const bh8*)(Vc + (dt * 16 + l) * 128 + (((hh * 4 + quad) ^ (l & 7)) * 16));
            __builtin_amdgcn_s_setprio(1);
            lacc = __builtin_amdgcn_mfma_f32_16x16x32_bf16(ones, pf, lacc, 0, 0, 0);
#pragma unroll
            for (int dt = 0; dt < 4; ++dt)
                oacc[dt] = __builtin_amdgcn_mfma_f32_16x16x32_bf16(vf[dt], pf, oacc[dt], 0, 0, 0);
            __builtin_amdgcn_s_setprio(0);
        }
        barrier_vm0();   // prefetch drained; all waves done with KT/VT cur
    }

    // ---- epilogue: normalize, write bf16 [B,T,H*D]; O^T: col=q(l), row=d ----
    {
        const float inv = 1.0f / lacc[0];
        const int t = q0 + w * 16 + l;
#pragma unroll
        for (int dt = 0; dt < 4; ++dt) {
            uint2 p;
            p.x = pack_rne(oacc[dt][0] * inv, oacc[dt][1] * inv);
            p.y = pack_rne(oacc[dt][2] * inv, oacc[dt][3] * inv);
            *(uint2*)(Og + ((size_t)(b * Tn + t)) * INNERn + h * 64 + dt * 16 + quad * 4) = p;
        }
    }
}

// ---------------------------------------------------------------------------
extern "C" void kernel_launch(void* const* d_in, const int* in_sizes, int n_in,
                              void* d_out, int out_size, void* d_ws, size_t ws_size,
                              hipStream_t stream)
{
    const float* x  = (const float*)d_in[0];
    const float* Wk = (const float*)d_in[1];
    const float* Wq = (const float*)d_in[2];
    const float* Wv = (const float*)d_in[3];
    const float* Wp = (const float*)d_in[4];
    float* out = (float*)d_out;

    // workspace (all bf16): x | Wk | Wq | Wv | Wp | q | k | vT | ao
    ushort* xb  = (ushort*)d_ws;
    ushort* wkb = xb  + (size_t)Mn * Cn;
    ushort* wqb = wkb + (size_t)INNERn * Cn;
    ushort* wvb = wqb + (size_t)INNERn * Cn;
    ushort* wpb = wvb + (size_t)INNERn * Cn;
    ushort* qw  = wpb + (size_t)OUTn * INNERn;
    ushort* kw  = qw  + (size_t)Mn * INNERn;
    ushort* vtw = kw  + (size_t)Mn * INNERn;   // [B,H,D,T]
    ushort* aow = vtw + (size_t)Mn * INNERn;

    const dim3 blk(256);
    cvt_all<<<dim3(8192 + 4096), blk, 0, stream>>>(x, Wk, Wq, Wv, Wp,
                                                   xb, wkb, wqb, wvb, wpb);

    // q folds d^-0.5 * log2(e) so softmax runs in exp2 domain
    gemm_qkv<<<dim3(1536), blk, 0, stream>>>(xb, wqb, wkb, wvb,
                                             qw, kw, vtw, 0.125f * 1.44269504f);

    attn_mfma<<<dim3(2048), blk, 0, stream>>>(qw, kw, vtw, aow);

    gemm_po<<<dim3(512), blk, 0, stream>>>(aow, wpb, out);
}

// Round 4
// 256.686 us; speedup vs baseline: 1.0608x; 1.0608x over previous
//
#include <hip/hip_runtime.h>
#include <math.h>

typedef __attribute__((ext_vector_type(8))) short bh8;    // 8 bf16 in 4 VGPRs
typedef __attribute__((ext_vector_type(4))) float f32x4;  // MFMA accumulator
typedef __attribute__((ext_vector_type(2))) unsigned u32x2;

namespace {
constexpr int Bn = 4, Tn = 2048, Cn = 1024, Hn = 16, Dn = 64, INNERn = 1024, OUTn = 1024;
constexpr int Mn = Bn * Tn;  // 8192 tokens
}

// async 16B global->LDS (wave-uniform base + lane*16 placement)
__device__ __forceinline__ void glds16(const void* g, void* l) {
    __builtin_amdgcn_global_load_lds(
        (const __attribute__((address_space(1))) void*)g,
        (__attribute__((address_space(3))) void*)l, 16, 0, 0);
}

// waitcnt vmcnt(0) lgkmcnt(0) + barrier — prefetch-friendly (loads issued at
// iter top are a full body old by the time we wait).
__device__ __forceinline__ void barrier_vm0() {
    __builtin_amdgcn_s_waitcnt(0x0070);
    __builtin_amdgcn_s_barrier();
}

// fp32 -> bf16 round-to-nearest-even
__device__ __forceinline__ ushort f2bf(float f) {
    union { float f; unsigned u; } v; v.f = f;
    unsigned r = v.u + 0x7fffu + ((v.u >> 16) & 1u);
    return (ushort)(r >> 16);
}
__device__ __forceinline__ unsigned pack_rne(float a, float b) {
    return (unsigned)f2bf(a) | ((unsigned)f2bf(b) << 16);
}
// truncation-pack: low16 = trunc(a), high16 = trunc(b)  (1 VALU op)
__device__ __forceinline__ unsigned pack_trunc(float a, float b) {
    return __builtin_amdgcn_perm(__float_as_uint(a), __float_as_uint(b), 0x03020706u);
}

// one launch: x (8192 blocks) + 4 weights (1024 blocks each)
__global__ __launch_bounds__(256)
void cvt_all(const float* __restrict__ x,  const float* __restrict__ Wk,
             const float* __restrict__ Wq, const float* __restrict__ Wv,
             const float* __restrict__ Wp,
             ushort* __restrict__ xb,  ushort* __restrict__ wkb,
             ushort* __restrict__ wqb, ushort* __restrict__ wvb,
             ushort* __restrict__ wpb)
{
    const int bid = blockIdx.x;
    const float* s; ushort* d; float sc; int i;
    if (bid < 8192) {
        s = x; d = xb; sc = 0.03125f;             // fold C^-0.5 (exact pow2)
        i = bid * 256 + threadIdx.x;
    } else {
        const int seg = (bid - 8192) >> 10;
        i = ((bid - 8192) & 1023) * 256 + threadIdx.x;
        s  = (seg == 0) ? Wk : (seg == 1) ? Wq : (seg == 2) ? Wv : Wp;
        d  = (seg == 0) ? wkb : (seg == 1) ? wqb : (seg == 2) ? wvb : wpb;
        sc = (seg == 3) ? 0.03125f : 1.0f;        // fold INNER^-0.5 into Wp
    }
    float4 f = ((const float4*)s)[i];
    ushort4 o;
    o.x = f2bf(f.x * sc); o.y = f2bf(f.y * sc);
    o.z = f2bf(f.z * sc); o.w = f2bf(f.w * sc);
    ((ushort4*)d)[i] = o;
}

// ---------------------------------------------------------------------------
// Fused QKV projection GEMM (128x128 tile, BK=32, dbuf, single vm0-barrier
// per K-iter). Q/K out: bf16 [B,H,T,D]; V out: bf16 [B,H,D,T] via LDS-staged
// coalesced stores. 1-D grid with XCD-grouped decode: blocks sharing an
// A-panel (same m-tile) land on the same XCD so the 256KB panel stays
// L2-resident across its 24 consumer blocks.  [R3: saved ~5us vs 2-D grid]
// ---------------------------------------------------------------------------
__global__ __launch_bounds__(256)
void gemm_qkv(const ushort* __restrict__ A, const ushort* __restrict__ Wq,
              const ushort* __restrict__ Wk, const ushort* __restrict__ Wv,
              ushort* __restrict__ Oq, ushort* __restrict__ Ok,
              ushort* __restrict__ Ovt, float qscale)
{
    __shared__ char SM[32768];     // As[2] | Bs[2]; reused for V^T epilogue
    char* As0 = SM;          char* As1 = SM + 8192;
    char* Bs0 = SM + 16384;  char* Bs1 = SM + 24576;
    const int tid = threadIdx.x;
    const int w = tid >> 6, lane = tid & 63, quad = lane >> 4, l = lane & 15;
    // XCD-grouped: 1536 blocks; xcd = lid&7; 8 m-panels per XCD x 24 n-blocks
    const int lid = blockIdx.x;
    const int xcd = lid & 7, j = lid >> 3;         // j in 0..191
    const int ytile = xcd * 8 + j / 24;            // m-tile 0..63
    const int xx = j % 24;                         // 0..23
    const int sel = xx >> 3;
    const ushort* Bw = (sel == 0) ? Wq : (sel == 1) ? Wk : Wv;
    const int n0 = (xx & 7) * 128, m0 = ytile * 128;
    const int wm = w >> 1, wn = w & 1;

    auto stage = [&](char* Ad, char* Bd, int k0) {
#pragma unroll
        for (int rr = 0; rr < 2; ++rr) {
            const int rho = w * 2 + rr;
            const int row = rho * 16 + (lane >> 2);
            const int kq  = (lane & 3) * 8;
            glds16(A  + (size_t)(m0 + row) * Cn + k0 + kq, Ad + rho * 1024 + lane * 16);
            glds16(Bw + (size_t)(n0 + row) * Cn + k0 + kq, Bd + rho * 1024 + lane * 16);
        }
    };

    f32x4 acc[4][4];
#pragma unroll
    for (int i = 0; i < 4; ++i)
#pragma unroll
        for (int j2 = 0; j2 < 4; ++j2) acc[i][j2] = (f32x4){0.f, 0.f, 0.f, 0.f};

    stage(As0, Bs0, 0);
    barrier_vm0();
#pragma unroll 2
    for (int it = 0; it < 32; ++it) {
        const int cur = it & 1;
        if (it < 31) stage(cur ? As0 : As1, cur ? Bs0 : Bs1, (it + 1) * 32);
        const char* Ac = cur ? As1 : As0; const char* Bc = cur ? Bs1 : Bs0;
        bh8 af[4], bf[4];
#pragma unroll
        for (int mf = 0; mf < 4; ++mf)
            af[mf] = *(const bh8*)(Ac + (wm * 64 + mf * 16 + l) * 64 + quad * 16);
#pragma unroll
        for (int nf = 0; nf < 4; ++nf)
            bf[nf] = *(const bh8*)(Bc + (wn * 64 + nf * 16 + l) * 64 + quad * 16);
#pragma unroll
        for (int mf = 0; mf < 4; ++mf)
#pragma unroll
            for (int nf = 0; nf < 4; ++nf)
                acc[mf][nf] = __builtin_amdgcn_mfma_f32_16x16x32_bf16(af[mf], bf[nf], acc[mf][nf], 0, 0, 0);
        barrier_vm0();
    }

    // epilogue: C/D layout col = l, row = quad*4 + reg
    if (sel < 2) {
        ushort* dU = (sel == 0) ? Oq : Ok;
        const float scale = (sel == 0) ? qscale : 1.0f;
#pragma unroll
        for (int mf = 0; mf < 4; ++mf)
#pragma unroll
            for (int nf = 0; nf < 4; ++nf) {
                const int mb = m0 + wm * 64 + mf * 16 + quad * 4;
                const int n  = n0 + wn * 64 + nf * 16 + l;
                const int h = n >> 6, dd = n & 63;
#pragma unroll
                for (int reg = 0; reg < 4; ++reg) {
                    const int m = mb + reg;
                    const int b = m >> 11, t = m & (Tn - 1);
                    dU[((size_t)(b * Hn + h) * Tn + t) * Dn + dd] = f2bf(acc[mf][nf][reg] * scale);
                }
            }
    } else {
        // V^T: stash tile [n][m] bf16 in LDS (XOR-swizzled 16B chunks), then
        // coalesced 256B-run stores into [B,H,D,T].
#pragma unroll
        for (int mf = 0; mf < 4; ++mf)
#pragma unroll
            for (int nf = 0; nf < 4; ++nf) {
                const int mb = wm * 64 + mf * 16 + quad * 4;   // tile-local m
                const int n  = wn * 64 + nf * 16 + l;          // tile-local n
                uint2 p;
                p.x = pack_rne(acc[mf][nf][0], acc[mf][nf][1]);
                p.y = pack_rne(acc[mf][nf][2], acc[mf][nf][3]);
                const int c = mb >> 3;                         // 16B chunk of m
                *(uint2*)(SM + n * 256 + ((c ^ (n & 15)) & 15) * 16 + (mb & 7) * 2) = p;
            }
        __syncthreads();
        const int bb = m0 >> 11, t0 = m0 & (Tn - 1);
#pragma unroll
        for (int it2 = 0; it2 < 8; ++it2) {
            const int n = it2 * 16 + w * 4 + quad;             // tile-local n
            const int ng = n0 + n;
            const int h = ng >> 6, dd = ng & 63;
            int4 vsm = *(const int4*)(SM + n * 256 + ((l ^ (n & 15)) & 15) * 16);
            *(int4*)(Ovt + ((size_t)(bb * Hn + h) * Dn + dd) * Tn + t0 + l * 8) = vsm;
        }
    }
}

// ---------------------------------------------------------------------------
// Output projection: out = ao(8192x1024) * Wp(1024x1024)^T, fp32 out.
// XCD-grouped 1-D grid: same-m-panel blocks co-XCD.
// ---------------------------------------------------------------------------
__global__ __launch_bounds__(256)
void gemm_po(const ushort* __restrict__ A, const ushort* __restrict__ Bw,
             float* __restrict__ Cout)
{
    __shared__ char As[2][8192];
    __shared__ char Bs[2][8192];
    const int tid = threadIdx.x;
    const int w = tid >> 6, lane = tid & 63, quad = lane >> 4, l = lane & 15;
    // 512 blocks: xcd = lid&7; 8 m-panels per XCD x 8 n-blocks
    const int lid = blockIdx.x;
    const int xcd = lid & 7, j = lid >> 3;         // j in 0..63
    const int n0 = (j & 7) * 128, m0 = (xcd * 8 + (j >> 3)) * 128;
    const int wm = w >> 1, wn = w & 1;

    auto stage = [&](int bsel, int k0) {
#pragma unroll
        for (int rr = 0; rr < 2; ++rr) {
            const int rho = w * 2 + rr;
            const int row = rho * 16 + (lane >> 2);
            const int kq  = (lane & 3) * 8;
            glds16(A  + (size_t)(m0 + row) * Cn + k0 + kq, As[bsel] + rho * 1024 + lane * 16);
            glds16(Bw + (size_t)(n0 + row) * Cn + k0 + kq, Bs[bsel] + rho * 1024 + lane * 16);
        }
    };

    f32x4 acc[4][4];
#pragma unroll
    for (int i = 0; i < 4; ++i)
#pragma unroll
        for (int j2 = 0; j2 < 4; ++j2) acc[i][j2] = (f32x4){0.f, 0.f, 0.f, 0.f};

    stage(0, 0);
    barrier_vm0();
#pragma unroll 2
    for (int it = 0; it < 32; ++it) {
        const int cur = it & 1;
        if (it < 31) stage(cur ^ 1, (it + 1) * 32);
        const char* Ac = As[cur]; const char* Bc = Bs[cur];
        bh8 af[4], bf[4];
#pragma unroll
        for (int mf = 0; mf < 4; ++mf)
            af[mf] = *(const bh8*)(Ac + (wm * 64 + mf * 16 + l) * 64 + quad * 16);
#pragma unroll
        for (int nf = 0; nf < 4; ++nf)
            bf[nf] = *(const bh8*)(Bc + (wn * 64 + nf * 16 + l) * 64 + quad * 16);
#pragma unroll
        for (int mf = 0; mf < 4; ++mf)
#pragma unroll
            for (int nf = 0; nf < 4; ++nf)
                acc[mf][nf] = __builtin_amdgcn_mfma_f32_16x16x32_bf16(af[mf], bf[nf], acc[mf][nf], 0, 0, 0);
        barrier_vm0();
    }

#pragma unroll
    for (int mf = 0; mf < 4; ++mf)
#pragma unroll
        for (int nf = 0; nf < 4; ++nf) {
            const int mb = m0 + wm * 64 + mf * 16 + quad * 4;
            const int n  = n0 + wn * 64 + nf * 16 + l;
#pragma unroll
            for (int reg = 0; reg < 4; ++reg)
                Cout[(size_t)(mb + reg) * OUTn + n] = acc[mf][nf][reg];
        }
}

// ---------------------------------------------------------------------------
// MFMA flash attention v8 = v6 body (QBLK=128, nt=2 — the efficient
// staging:compute ratio; v7's QBLK=64 doubled staging for no occupancy gain)
// + XCD-grouped bh decode (v7's proven FETCH 139MB->25MB: K/V L2-resident,
// prefetch latency ~900->~200cy) + s_setprio(1) around MFMA clusters (T5).
// In-register P transpose via permlane32/16_swap. K/V double-buffered
// (glds prefetch + single vm0-barrier per iter). LDS 32KB.
// Grid 1024 = 8 XCD x 8 bh x 16 q-tiles.
// ---------------------------------------------------------------------------
__global__ __launch_bounds__(256, 4)
void attn_mfma(const ushort* __restrict__ Qg, const ushort* __restrict__ Kg,
               const ushort* __restrict__ Vtg, ushort* __restrict__ Og)
{
    __shared__ char KT[2][8192];  // (r,d): r*128 + (((d>>3) ^ (r&7))<<4) + (d&7)*2
    __shared__ char VT[2][8192];  // (c,d): d*128 + ((c>>3)^(d&7))*16 + (c&7)*2

    const int tid = threadIdx.x;
    const int w = tid >> 6, lane = tid & 63, quad = lane >> 4, l = lane & 15;
    // XCD-grouped decode: 1024 blocks; xcd = lid&7; 8 bh per XCD x 16 q-tiles
    const int lid = blockIdx.x;
    const int xcd = lid & 7, j = lid >> 3;         // j in 0..127
    const int bh = (xcd << 3) | (j >> 4);          // 0..63
    const int q0 = (j & 15) * 128;
    const int b = bh >> 4, h = bh & 15;
    const ushort* Qp = Qg  + (size_t)bh * Tn * Dn;
    const ushort* Kp = Kg  + (size_t)bh * Tn * Dn;
    const ushort* Vp = Vtg + (size_t)bh * Dn * Tn;   // [d][t]

    auto stageK = [&](char* buf, int kt) {
#pragma unroll
        for (int rr = 0; rr < 2; ++rr) {
            const int rho = w * 2 + rr;                    // 0..7, 8 rows each
            const int r8  = lane >> 3;                     // row within block
            const int r   = rho * 8 + r8;                  // key row 0..63
            const int dc  = (lane & 7) ^ r8;               // pre-swizzled chunk
            glds16(Kp + (size_t)(kt * 64 + r) * Dn + dc * 8, buf + rho * 1024 + lane * 16);
        }
    };
    auto stageV = [&](char* buf, int kt) {
#pragma unroll
        for (int rr = 0; rr < 2; ++rr) {
            const int rho = w * 2 + rr;
            const int d = rho * 8 + (lane >> 3);           // 0..63
            const int csrc = (lane & 7) ^ ((lane >> 3) & 7);
            glds16(Vp + (size_t)d * Tn + kt * 64 + csrc * 8, buf + rho * 1024 + lane * 16);
        }
    };

    // ---- Q frags direct from global (B-operand layout; once per block) ----
    bh8 qf[2][2];
#pragma unroll
    for (int nt = 0; nt < 2; ++nt)
#pragma unroll
        for (int ks = 0; ks < 2; ++ks)
            qf[nt][ks] = *(const bh8*)(Qp + (size_t)(q0 + w * 32 + nt * 16 + l) * Dn + ks * 32 + quad * 8);

    bh8 ones;
#pragma unroll
    for (int i = 0; i < 8; ++i) ones[i] = (short)0x3F80;   // bf16 1.0

    f32x4 oacc[2][4], lacc[2];
#pragma unroll
    for (int nt = 0; nt < 2; ++nt) {
        lacc[nt] = (f32x4){0.f, 0.f, 0.f, 0.f};
#pragma unroll
        for (int dt = 0; dt < 4; ++dt) oacc[nt][dt] = (f32x4){0.f, 0.f, 0.f, 0.f};
    }

    const f32x4 zero = (f32x4){0.f, 0.f, 0.f, 0.f};

    stageK(KT[0], 0);
    stageV(VT[0], 0);
    barrier_vm0();

#pragma unroll 2
    for (int kt = 0; kt < Tn / 64; ++kt) {
        const int cur = kt & 1;
        if (kt < Tn / 64 - 1) {           // prefetch next tile (in flight all body)
            stageK(KT[cur ^ 1], kt + 1);
            stageV(VT[cur ^ 1], kt + 1);
        }
        const char* Kc = KT[cur];
        const char* Vc = VT[cur];

        // ---- two 32-key halves: S -> exp -> in-reg transpose -> PV ----
#pragma unroll
        for (int hh = 0; hh < 2; ++hh) {
            // K frags for keys hh*32..+31 (A-operand: m=key, k=d)
            // KT read with the same XOR the staging applied: row&7 == l&7.
            bh8 kf[2][2];
#pragma unroll
            for (int k8l = 0; k8l < 2; ++k8l) {
                const int row = (hh * 2 + k8l) * 16 + l;
#pragma unroll
                for (int ks = 0; ks < 2; ++ks)
                    kf[k8l][ks] = *(const bh8*)(Kc + row * 128 + (((ks * 4 + quad) ^ (l & 7)) * 16));
            }

            // S^T = K Q^T : rows=keys(quad*4+reg), col=q(l)
            f32x4 st[2][2];
            __builtin_amdgcn_s_setprio(1);
#pragma unroll
            for (int nt = 0; nt < 2; ++nt)
#pragma unroll
                for (int k8l = 0; k8l < 2; ++k8l) {
                    st[nt][k8l] = __builtin_amdgcn_mfma_f32_16x16x32_bf16(kf[k8l][0], qf[nt][0], zero, 0, 0, 0);
                    st[nt][k8l] = __builtin_amdgcn_mfma_f32_16x16x32_bf16(kf[k8l][1], qf[nt][1], st[nt][k8l], 0, 0, 0);
                }
            __builtin_amdgcn_s_setprio(0);

            // P = exp2(S) -> trunc-bf16 pairs -> permlane transpose to
            // B-operand layout (keys quad*8+j, q=l), all in registers.
            bh8 pf[2];
#pragma unroll
            for (int nt = 0; nt < 2; ++nt) {
                const unsigned a0 = pack_trunc(__builtin_amdgcn_exp2f(st[nt][0][0]),
                                               __builtin_amdgcn_exp2f(st[nt][0][1]));
                const unsigned a1 = pack_trunc(__builtin_amdgcn_exp2f(st[nt][0][2]),
                                               __builtin_amdgcn_exp2f(st[nt][0][3]));
                const unsigned b0 = pack_trunc(__builtin_amdgcn_exp2f(st[nt][1][0]),
                                               __builtin_amdgcn_exp2f(st[nt][1][1]));
                const unsigned b1 = pack_trunc(__builtin_amdgcn_exp2f(st[nt][1][2]),
                                               __builtin_amdgcn_exp2f(st[nt][1][3]));
                const u32x2 p = __builtin_amdgcn_permlane32_swap(a0, b0, false, false);
                const u32x2 q = __builtin_amdgcn_permlane16_swap(p.x, p.y, false, false);
                const u32x2 r = __builtin_amdgcn_permlane32_swap(a1, b1, false, false);
                const u32x2 s = __builtin_amdgcn_permlane16_swap(r.x, r.y, false, false);
                union { unsigned u[4]; bh8 v; } pu;
                pu.u[0] = q.x; pu.u[1] = s.x; pu.u[2] = q.y; pu.u[3] = s.y;
                pf[nt] = pu.v;
            }

            // O += P V ; l += ones*P (B-operand pf: n=q, k=keys of half)
            bh8 vf[4];
#pragma unroll
            for (int dt = 0; dt < 4; ++dt)
                vf[dt] = *(const bh8*)(Vc + (dt * 16 + l) * 128 + (((hh * 4 + quad) ^ (l & 7)) * 16));
            __builtin_amdgcn_s_setprio(1);
#pragma unroll
            for (int nt = 0; nt < 2; ++nt)
                lacc[nt] = __builtin_amdgcn_mfma_f32_16x16x32_bf16(ones, pf[nt], lacc[nt], 0, 0, 0);
#pragma unroll
            for (int dt = 0; dt < 4; ++dt)
#pragma unroll
                for (int nt = 0; nt < 2; ++nt)
                    oacc[nt][dt] = __builtin_amdgcn_mfma_f32_16x16x32_bf16(vf[dt], pf[nt], oacc[nt][dt], 0, 0, 0);
            __builtin_amdgcn_s_setprio(0);
        }
        barrier_vm0();   // prefetch drained; all waves done with KT/VT cur
    }

    // ---- epilogue: normalize, write bf16 [B,T,H*D]; O^T: col=q(l), row=d ----
#pragma unroll
    for (int nt = 0; nt < 2; ++nt) {
        const float inv = 1.0f / lacc[nt][0];
        const int t = q0 + w * 32 + nt * 16 + l;
#pragma unroll
        for (int dt = 0; dt < 4; ++dt) {
            uint2 p;
            p.x = pack_rne(oacc[nt][dt][0] * inv, oacc[nt][dt][1] * inv);
            p.y = pack_rne(oacc[nt][dt][2] * inv, oacc[nt][dt][3] * inv);
            *(uint2*)(Og + ((size_t)(b * Tn + t)) * INNERn + h * 64 + dt * 16 + quad * 4) = p;
        }
    }
}

// ---------------------------------------------------------------------------
extern "C" void kernel_launch(void* const* d_in, const int* in_sizes, int n_in,
                              void* d_out, int out_size, void* d_ws, size_t ws_size,
                              hipStream_t stream)
{
    const float* x  = (const float*)d_in[0];
    const float* Wk = (const float*)d_in[1];
    const float* Wq = (const float*)d_in[2];
    const float* Wv = (const float*)d_in[3];
    const float* Wp = (const float*)d_in[4];
    float* out = (float*)d_out;

    // workspace (all bf16): x | Wk | Wq | Wv | Wp | q | k | vT | ao
    ushort* xb  = (ushort*)d_ws;
    ushort* wkb = xb  + (size_t)Mn * Cn;
    ushort* wqb = wkb + (size_t)INNERn * Cn;
    ushort* wvb = wqb + (size_t)INNERn * Cn;
    ushort* wpb = wvb + (size_t)INNERn * Cn;
    ushort* qw  = wpb + (size_t)OUTn * INNERn;
    ushort* kw  = qw  + (size_t)Mn * INNERn;
    ushort* vtw = kw  + (size_t)Mn * INNERn;   // [B,H,D,T]
    ushort* aow = vtw + (size_t)Mn * INNERn;

    const dim3 blk(256);
    cvt_all<<<dim3(8192 + 4096), blk, 0, stream>>>(x, Wk, Wq, Wv, Wp,
                                                   xb, wkb, wqb, wvb, wpb);

    // q folds d^-0.5 * log2(e) so softmax runs in exp2 domain
    gemm_qkv<<<dim3(1536), blk, 0, stream>>>(xb, wqb, wkb, wvb,
                                             qw, kw, vtw, 0.125f * 1.44269504f);

    attn_mfma<<<dim3(1024), blk, 0, stream>>>(qw, kw, vtw, aow);

    gemm_po<<<dim3(512), blk, 0, stream>>>(aow, wpb, out);
}

// Round 5
// 254.943 us; speedup vs baseline: 1.0681x; 1.0068x over previous
//
#include <hip/hip_runtime.h>
#include <math.h>

typedef __attribute__((ext_vector_type(8))) short bh8;    // 8 bf16 in 4 VGPRs
typedef __attribute__((ext_vector_type(4))) float f32x4;  // MFMA accumulator
typedef __attribute__((ext_vector_type(2))) unsigned u32x2;

namespace {
constexpr int Bn = 4, Tn = 2048, Cn = 1024, Hn = 16, Dn = 64, INNERn = 1024, OUTn = 1024;
constexpr int Mn = Bn * Tn;  // 8192 tokens
}

// async 16B global->LDS (wave-uniform base + lane*16 placement)
__device__ __forceinline__ void glds16(const void* g, void* l) {
    __builtin_amdgcn_global_load_lds(
        (const __attribute__((address_space(1))) void*)g,
        (__attribute__((address_space(3))) void*)l, 16, 0, 0);
}

// waitcnt vmcnt(0) lgkmcnt(0) + barrier
__device__ __forceinline__ void barrier_vm0() {
    __builtin_amdgcn_s_waitcnt(0x0070);
    __builtin_amdgcn_s_barrier();
}

// fp32 -> bf16 round-to-nearest-even
__device__ __forceinline__ ushort f2bf(float f) {
    union { float f; unsigned u; } v; v.f = f;
    unsigned r = v.u + 0x7fffu + ((v.u >> 16) & 1u);
    return (ushort)(r >> 16);
}
__device__ __forceinline__ unsigned pack_rne(float a, float b) {
    return (unsigned)f2bf(a) | ((unsigned)f2bf(b) << 16);
}
// truncation-pack: low16 = trunc(a), high16 = trunc(b)  (1 VALU op)
__device__ __forceinline__ unsigned pack_trunc(float a, float b) {
    return __builtin_amdgcn_perm(__float_as_uint(a), __float_as_uint(b), 0x03020706u);
}

// one launch: x (8192 blocks) + 4 weights (1024 blocks each)
__global__ __launch_bounds__(256)
void cvt_all(const float* __restrict__ x,  const float* __restrict__ Wk,
             const float* __restrict__ Wq, const float* __restrict__ Wv,
             const float* __restrict__ Wp,
             ushort* __restrict__ xb,  ushort* __restrict__ wkb,
             ushort* __restrict__ wqb, ushort* __restrict__ wvb,
             ushort* __restrict__ wpb)
{
    const int bid = blockIdx.x;
    const float* s; ushort* d; float sc; int i;
    if (bid < 8192) {
        s = x; d = xb; sc = 0.03125f;             // fold C^-0.5 (exact pow2)
        i = bid * 256 + threadIdx.x;
    } else {
        const int seg = (bid - 8192) >> 10;
        i = ((bid - 8192) & 1023) * 256 + threadIdx.x;
        s  = (seg == 0) ? Wk : (seg == 1) ? Wq : (seg == 2) ? Wv : Wp;
        d  = (seg == 0) ? wkb : (seg == 1) ? wqb : (seg == 2) ? wvb : wpb;
        sc = (seg == 3) ? 0.03125f : 1.0f;        // fold INNER^-0.5 into Wp
    }
    float4 f = ((const float4*)s)[i];
    ushort4 o;
    o.x = f2bf(f.x * sc); o.y = f2bf(f.y * sc);
    o.z = f2bf(f.z * sc); o.w = f2bf(f.w * sc);
    ((ushort4*)d)[i] = o;
}

// ---------------------------------------------------------------------------
// 256x256-tile GEMM core, 512 threads = 8 waves (2M x 4N), BK=32.
// Phase-split schedule with counted vmcnt (T3+T4) + LDS XOR swizzle (T2)
// + setprio around MFMA clusters (T5).
//
// LDS (64KB): A[2 dbuf][2 half][128 rows][64B] @0 ; B same @32768.
// Swizzle: 16B slot' = slot ^ ((row>>1)&3), applied on BOTH sides:
//   stage: glds dest linear (tid*16), global source k-chunk = slot^((row>>1)&3)
//   read:  byte = row*64 + ((quad ^ ((l>>1)&3))*16)
// => each 16-lane quad covers all 8 mod-128 bank positions (2-way, free).
//
// Per K-tile t (2 phases):
//  P1: ds_read af[0..3],bf[0..3]; stage A(t+1)->buf[(t+1)&1] (other buf,
//      drained during t-1); barrier; lgkm0; 16 MFMA (mf0-3); barrier.
//  P2: ds_read ag[0..3]=af[4..7]; stage B(t+2)->buf[t&1] (B region last read
//      at P1, drained by P1 lgkm0+barrier); barrier; lgkm0; 16 MFMA (mf4-7);
//      vmcnt(2); barrier.
// vmcnt(2) leaves only B(t+2) outstanding => A(t+1),B(t+1) complete before
// t+1.P1 reads them. Prologue stages B(0),A(0),B(1) then vmcnt(2).
// ---------------------------------------------------------------------------
__device__ __forceinline__ void gemm256_core(const ushort* __restrict__ A,
                                             const ushort* __restrict__ Bw,
                                             const int m0, const int n0,
                                             char* LDS_, f32x4 (&acc)[8][4])
{
    const int tid = threadIdx.x;
    const int w = tid >> 6, lane = tid & 63, quad = lane >> 4, l = lane & 15;
    const int wm = w >> 2, wn = w & 3;

    auto stageHalf = [&](int isB, int dbuf, int half, int rowg0, int kt) {
        char* base = LDS_ + isB * 32768 + dbuf * 16384 + half * 8192;
        const ushort* G = isB ? Bw : A;
        const int row = tid >> 2, slot = tid & 3;
        glds16(G + (size_t)(rowg0 + half * 128 + row) * Cn + kt * 32
                 + ((slot ^ ((tid >> 3) & 3)) * 8),
               base + tid * 16);
    };
    auto ldA = [&](int dbuf, int mf) -> bh8 {
        return *(const bh8*)(LDS_ + dbuf * 16384 + wm * 8192
                             + (mf * 16 + l) * 64
                             + ((quad ^ ((l >> 1) & 3)) * 16));
    };
    auto ldB = [&](int dbuf, int nf) -> bh8 {
        return *(const bh8*)(LDS_ + 32768 + dbuf * 16384 + (wn >> 1) * 8192
                             + ((wn & 1) * 64 + nf * 16 + l) * 64
                             + ((quad ^ ((l >> 1) & 3)) * 16));
    };

    // prologue: B(0) both halves, A(0) both halves, B(1) both halves
    stageHalf(1, 0, 0, n0, 0); stageHalf(1, 0, 1, n0, 0);
    stageHalf(0, 0, 0, m0, 0); stageHalf(0, 0, 1, m0, 0);
    stageHalf(1, 1, 0, n0, 1); stageHalf(1, 1, 1, n0, 1);
    __builtin_amdgcn_s_waitcnt(0x0F72);   // vmcnt(2): tile0 fully staged
    __builtin_amdgcn_s_barrier();

#pragma unroll 2
    for (int t = 0; t < 32; ++t) {
        const int d = t & 1;
        bh8 af[4], bf[4], ag[4];
        // ---- P1 ----
#pragma unroll
        for (int mf = 0; mf < 4; ++mf) af[mf] = ldA(d, mf);
#pragma unroll
        for (int nf = 0; nf < 4; ++nf) bf[nf] = ldB(d, nf);
        if (t + 1 < 32) {
            stageHalf(0, (t + 1) & 1, 0, m0, t + 1);
            stageHalf(0, (t + 1) & 1, 1, m0, t + 1);
        }
        __builtin_amdgcn_s_barrier();
        __builtin_amdgcn_s_waitcnt(0xC07F);       // lgkmcnt(0)
        __builtin_amdgcn_s_setprio(1);
#pragma unroll
        for (int mf = 0; mf < 4; ++mf)
#pragma unroll
            for (int nf = 0; nf < 4; ++nf)
                acc[mf][nf] = __builtin_amdgcn_mfma_f32_16x16x32_bf16(af[mf], bf[nf], acc[mf][nf], 0, 0, 0);
        __builtin_amdgcn_s_setprio(0);
        __builtin_amdgcn_s_barrier();
        // ---- P2 ----
#pragma unroll
        for (int mf = 0; mf < 4; ++mf) ag[mf] = ldA(d, mf + 4);
        if (t + 2 < 32) {
            stageHalf(1, d, 0, n0, t + 2);
            stageHalf(1, d, 1, n0, t + 2);
        }
        __builtin_amdgcn_s_barrier();
        __builtin_amdgcn_s_waitcnt(0xC07F);       // lgkmcnt(0)
        __builtin_amdgcn_s_setprio(1);
#pragma unroll
        for (int mf = 0; mf < 4; ++mf)
#pragma unroll
            for (int nf = 0; nf < 4; ++nf)
                acc[mf + 4][nf] = __builtin_amdgcn_mfma_f32_16x16x32_bf16(ag[mf], bf[nf], acc[mf + 4][nf], 0, 0, 0);
        __builtin_amdgcn_s_setprio(0);
        if (t + 2 < 32) __builtin_amdgcn_s_waitcnt(0x0F72);  // vmcnt(2), counted
        else            __builtin_amdgcn_s_waitcnt(0x0F70);  // tail drain
        __builtin_amdgcn_s_barrier();
    }
}

// ---------------------------------------------------------------------------
// Fused QKV projection GEMM on the 256^2 core. Grid 384 = 8 XCD x (4 m-tiles
// x 3 sel x 4 n-tiles): same-m-panel blocks co-XCD (A panel L2-resident).
// Q/K out: bf16 [B,H,T,D] scatter; V out: bf16 [B,H,D,T] via LDS-staged
// coalesced stores per 128^2 sub-tile (reuses drained main-loop LDS).
// ---------------------------------------------------------------------------
__global__ __launch_bounds__(512, 2)
void gemm_qkv(const ushort* __restrict__ A, const ushort* __restrict__ Wq,
              const ushort* __restrict__ Wk, const ushort* __restrict__ Wv,
              ushort* __restrict__ Oq, ushort* __restrict__ Ok,
              ushort* __restrict__ Ovt, float qscale)
{
    __shared__ char LDS_[65536];
    const int tid = threadIdx.x;
    const int w = tid >> 6, lane = tid & 63, quad = lane >> 4, l = lane & 15;
    const int wm = w >> 2, wn = w & 3;
    const int lid = blockIdx.x;
    const int xcd = lid & 7, j = lid >> 3;         // j in 0..47
    const int mt = xcd * 4 + j / 12;               // 0..31
    const int rest = j % 12;
    const int sel = rest >> 2, ntile = rest & 3;
    const ushort* Bw = (sel == 0) ? Wq : (sel == 1) ? Wk : Wv;
    const int m0 = mt * 256, n0 = ntile * 256;

    f32x4 acc[8][4];
#pragma unroll
    for (int i = 0; i < 8; ++i)
#pragma unroll
        for (int j2 = 0; j2 < 4; ++j2) acc[i][j2] = (f32x4){0.f, 0.f, 0.f, 0.f};

    gemm256_core(A, Bw, m0, n0, LDS_, acc);

    if (sel < 2) {
        ushort* dU = (sel == 0) ? Oq : Ok;
        const float scale = (sel == 0) ? qscale : 1.0f;
#pragma unroll
        for (int mf = 0; mf < 8; ++mf)
#pragma unroll
            for (int nf = 0; nf < 4; ++nf) {
                const int mb = m0 + wm * 128 + mf * 16 + quad * 4;
                const int n  = n0 + wn * 64 + nf * 16 + l;
                const int h = n >> 6, dd = n & 63;
#pragma unroll
                for (int reg = 0; reg < 4; ++reg) {
                    const int m = mb + reg;
                    const int b = m >> 11, t = m & (Tn - 1);
                    dU[((size_t)(b * Hn + h) * Tn + t) * Dn + dd] = f2bf(acc[mf][nf][reg] * scale);
                }
            }
    } else {
        // V^T: per 128x128 sub-tile, stash [n][m] bf16 (n-XOR chunk swizzle)
        // then coalesced 256B-run stores into [B,H,D,T].
#pragma unroll
        for (int sm = 0; sm < 2; ++sm)
#pragma unroll
            for (int sn = 0; sn < 2; ++sn) {
                __builtin_amdgcn_s_barrier();      // prev sub-tile readers done
                if (wm == sm && (wn >> 1) == sn) {
#pragma unroll
                    for (int mf = 0; mf < 8; ++mf)
#pragma unroll
                        for (int nf = 0; nf < 4; ++nf) {
                            const int mbL = mf * 16 + quad * 4;            // 0..127
                            const int nL  = (wn & 1) * 64 + nf * 16 + l;   // 0..127
                            uint2 p;
                            p.x = pack_rne(acc[mf][nf][0], acc[mf][nf][1]);
                            p.y = pack_rne(acc[mf][nf][2], acc[mf][nf][3]);
                            const int c = mbL >> 3;
                            *(uint2*)(LDS_ + nL * 256 + ((c ^ (nL & 15)) & 15) * 16 + (mbL & 7) * 2) = p;
                        }
                }
                __builtin_amdgcn_s_waitcnt(0xC07F);   // drain ds_writes
                __builtin_amdgcn_s_barrier();
                const int bb = (m0 + sm * 128) >> 11, t0 = (m0 + sm * 128) & (Tn - 1);
#pragma unroll
                for (int it2 = 0; it2 < 4; ++it2) {
                    const int nL = it2 * 32 + w * 4 + quad;                // 0..127
                    const int ng = n0 + sn * 128 + nL;
                    const int h = ng >> 6, dd = ng & 63;
                    int4 vsm = *(const int4*)(LDS_ + nL * 256 + ((l ^ (nL & 15)) & 15) * 16);
                    *(int4*)(Ovt + ((size_t)(bb * Hn + h) * Dn + dd) * Tn + t0 + l * 8) = vsm;
                }
            }
    }
}

// ---------------------------------------------------------------------------
// Output projection: out = ao(8192x1024) * Wp(1024x1024)^T, fp32 out.
// XCD-grouped 1-D grid: same-m-panel blocks co-XCD. (128^2 tile; 8-phase
// conversion pending gemm_qkv validation.)
// ---------------------------------------------------------------------------
__global__ __launch_bounds__(256)
void gemm_po(const ushort* __restrict__ A, const ushort* __restrict__ Bw,
             float* __restrict__ Cout)
{
    __shared__ char As[2][8192];
    __shared__ char Bs[2][8192];
    const int tid = threadIdx.x;
    const int w = tid >> 6, lane = tid & 63, quad = lane >> 4, l = lane & 15;
    // 512 blocks: xcd = lid&7; 8 m-panels per XCD x 8 n-blocks
    const int lid = blockIdx.x;
    const int xcd = lid & 7, j = lid >> 3;         // j in 0..63
    const int n0 = (j & 7) * 128, m0 = (xcd * 8 + (j >> 3)) * 128;
    const int wm = w >> 1, wn = w & 1;

    auto stage = [&](int bsel, int k0) {
#pragma unroll
        for (int rr = 0; rr < 2; ++rr) {
            const int rho = w * 2 + rr;
            const int row = rho * 16 + (lane >> 2);
            const int kq  = (lane & 3) * 8;
            glds16(A  + (size_t)(m0 + row) * Cn + k0 + kq, As[bsel] + rho * 1024 + lane * 16);
            glds16(Bw + (size_t)(n0 + row) * Cn + k0 + kq, Bs[bsel] + rho * 1024 + lane * 16);
        }
    };

    f32x4 acc[4][4];
#pragma unroll
    for (int i = 0; i < 4; ++i)
#pragma unroll
        for (int j2 = 0; j2 < 4; ++j2) acc[i][j2] = (f32x4){0.f, 0.f, 0.f, 0.f};

    stage(0, 0);
    barrier_vm0();
#pragma unroll 2
    for (int it = 0; it < 32; ++it) {
        const int cur = it & 1;
        if (it < 31) stage(cur ^ 1, (it + 1) * 32);
        const char* Ac = As[cur]; const char* Bc = Bs[cur];
        bh8 af[4], bf[4];
#pragma unroll
        for (int mf = 0; mf < 4; ++mf)
            af[mf] = *(const bh8*)(Ac + (wm * 64 + mf * 16 + l) * 64 + quad * 16);
#pragma unroll
        for (int nf = 0; nf < 4; ++nf)
            bf[nf] = *(const bh8*)(Bc + (wn * 64 + nf * 16 + l) * 64 + quad * 16);
#pragma unroll
        for (int mf = 0; mf < 4; ++mf)
#pragma unroll
            for (int nf = 0; nf < 4; ++nf)
                acc[mf][nf] = __builtin_amdgcn_mfma_f32_16x16x32_bf16(af[mf], bf[nf], acc[mf][nf], 0, 0, 0);
        barrier_vm0();
    }

#pragma unroll
    for (int mf = 0; mf < 4; ++mf)
#pragma unroll
        for (int nf = 0; nf < 4; ++nf) {
            const int mb = m0 + wm * 64 + mf * 16 + quad * 4;
            const int n  = n0 + wn * 64 + nf * 16 + l;
#pragma unroll
            for (int reg = 0; reg < 4; ++reg)
                Cout[(size_t)(mb + reg) * OUTn + n] = acc[mf][nf][reg];
        }
}

// ---------------------------------------------------------------------------
// MFMA flash attention v8 (unchanged from R4): QBLK=128, XCD-grouped bh
// decode (K/V L2-resident), in-register P transpose via permlane swaps,
// setprio around MFMA clusters. K/V double-buffered, LDS 32KB.
// Grid 1024 = 8 XCD x 8 bh x 16 q-tiles.
// ---------------------------------------------------------------------------
__global__ __launch_bounds__(256, 4)
void attn_mfma(const ushort* __restrict__ Qg, const ushort* __restrict__ Kg,
               const ushort* __restrict__ Vtg, ushort* __restrict__ Og)
{
    __shared__ char KT[2][8192];  // (r,d): r*128 + (((d>>3) ^ (r&7))<<4) + (d&7)*2
    __shared__ char VT[2][8192];  // (c,d): d*128 + ((c>>3)^(d&7))*16 + (c&7)*2

    const int tid = threadIdx.x;
    const int w = tid >> 6, lane = tid & 63, quad = lane >> 4, l = lane & 15;
    const int lid = blockIdx.x;
    const int xcd = lid & 7, j = lid >> 3;         // j in 0..127
    const int bh = (xcd << 3) | (j >> 4);          // 0..63
    const int q0 = (j & 15) * 128;
    const int b = bh >> 4, h = bh & 15;
    const ushort* Qp = Qg  + (size_t)bh * Tn * Dn;
    const ushort* Kp = Kg  + (size_t)bh * Tn * Dn;
    const ushort* Vp = Vtg + (size_t)bh * Dn * Tn;   // [d][t]

    auto stageK = [&](char* buf, int kt) {
#pragma unroll
        for (int rr = 0; rr < 2; ++rr) {
            const int rho = w * 2 + rr;                    // 0..7, 8 rows each
            const int r8  = lane >> 3;                     // row within block
            const int r   = rho * 8 + r8;                  // key row 0..63
            const int dc  = (lane & 7) ^ r8;               // pre-swizzled chunk
            glds16(Kp + (size_t)(kt * 64 + r) * Dn + dc * 8, buf + rho * 1024 + lane * 16);
        }
    };
    auto stageV = [&](char* buf, int kt) {
#pragma unroll
        for (int rr = 0; rr < 2; ++rr) {
            const int rho = w * 2 + rr;
            const int d = rho * 8 + (lane >> 3);           // 0..63
            const int csrc = (lane & 7) ^ ((lane >> 3) & 7);
            glds16(Vp + (size_t)d * Tn + kt * 64 + csrc * 8, buf + rho * 1024 + lane * 16);
        }
    };

    // ---- Q frags direct from global (B-operand layout; once per block) ----
    bh8 qf[2][2];
#pragma unroll
    for (int nt = 0; nt < 2; ++nt)
#pragma unroll
        for (int ks = 0; ks < 2; ++ks)
            qf[nt][ks] = *(const bh8*)(Qp + (size_t)(q0 + w * 32 + nt * 16 + l) * Dn + ks * 32 + quad * 8);

    bh8 ones;
#pragma unroll
    for (int i = 0; i < 8; ++i) ones[i] = (short)0x3F80;   // bf16 1.0

    f32x4 oacc[2][4], lacc[2];
#pragma unroll
    for (int nt = 0; nt < 2; ++nt) {
        lacc[nt] = (f32x4){0.f, 0.f, 0.f, 0.f};
#pragma unroll
        for (int dt = 0; dt < 4; ++dt) oacc[nt][dt] = (f32x4){0.f, 0.f, 0.f, 0.f};
    }

    const f32x4 zero = (f32x4){0.f, 0.f, 0.f, 0.f};

    stageK(KT[0], 0);
    stageV(VT[0], 0);
    barrier_vm0();

#pragma unroll 2
    for (int kt = 0; kt < Tn / 64; ++kt) {
        const int cur = kt & 1;
        if (kt < Tn / 64 - 1) {           // prefetch next tile (in flight all body)
            stageK(KT[cur ^ 1], kt + 1);
            stageV(VT[cur ^ 1], kt + 1);
        }
        const char* Kc = KT[cur];
        const char* Vc = VT[cur];

        // ---- two 32-key halves: S -> exp -> in-reg transpose -> PV ----
#pragma unroll
        for (int hh = 0; hh < 2; ++hh) {
            bh8 kf[2][2];
#pragma unroll
            for (int k8l = 0; k8l < 2; ++k8l) {
                const int row = (hh * 2 + k8l) * 16 + l;
#pragma unroll
                for (int ks = 0; ks < 2; ++ks)
                    kf[k8l][ks] = *(const bh8*)(Kc + row * 128 + (((ks * 4 + quad) ^ (l & 7)) * 16));
            }

            // S^T = K Q^T : rows=keys(quad*4+reg), col=q(l)
            f32x4 st[2][2];
            __builtin_amdgcn_s_setprio(1);
#pragma unroll
            for (int nt = 0; nt < 2; ++nt)
#pragma unroll
                for (int k8l = 0; k8l < 2; ++k8l) {
                    st[nt][k8l] = __builtin_amdgcn_mfma_f32_16x16x32_bf16(kf[k8l][0], qf[nt][0], zero, 0, 0, 0);
                    st[nt][k8l] = __builtin_amdgcn_mfma_f32_16x16x32_bf16(kf[k8l][1], qf[nt][1], st[nt][k8l], 0, 0, 0);
                }
            __builtin_amdgcn_s_setprio(0);

            // P = exp2(S) -> trunc-bf16 pairs -> permlane transpose to
            // B-operand layout (keys quad*8+j, q=l), all in registers.
            bh8 pf[2];
#pragma unroll
            for (int nt = 0; nt < 2; ++nt) {
                const unsigned a0 = pack_trunc(__builtin_amdgcn_exp2f(st[nt][0][0]),
                                               __builtin_amdgcn_exp2f(st[nt][0][1]));
                const unsigned a1 = pack_trunc(__builtin_amdgcn_exp2f(st[nt][0][2]),
                                               __builtin_amdgcn_exp2f(st[nt][0][3]));
                const unsigned b0 = pack_trunc(__builtin_amdgcn_exp2f(st[nt][1][0]),
                                               __builtin_amdgcn_exp2f(st[nt][1][1]));
                const unsigned b1 = pack_trunc(__builtin_amdgcn_exp2f(st[nt][1][2]),
                                               __builtin_amdgcn_exp2f(st[nt][1][3]));
                const u32x2 p = __builtin_amdgcn_permlane32_swap(a0, b0, false, false);
                const u32x2 q = __builtin_amdgcn_permlane16_swap(p.x, p.y, false, false);
                const u32x2 r = __builtin_amdgcn_permlane32_swap(a1, b1, false, false);
                const u32x2 s = __builtin_amdgcn_permlane16_swap(r.x, r.y, false, false);
                union { unsigned u[4]; bh8 v; } pu;
                pu.u[0] = q.x; pu.u[1] = s.x; pu.u[2] = q.y; pu.u[3] = s.y;
                pf[nt] = pu.v;
            }

            // O += P V ; l += ones*P (B-operand pf: n=q, k=keys of half)
            bh8 vf[4];
#pragma unroll
            for (int dt = 0; dt < 4; ++dt)
                vf[dt] = *(const bh8*)(Vc + (dt * 16 + l) * 128 + (((hh * 4 + quad) ^ (l & 7)) * 16));
            __builtin_amdgcn_s_setprio(1);
#pragma unroll
            for (int nt = 0; nt < 2; ++nt)
                lacc[nt] = __builtin_amdgcn_mfma_f32_16x16x32_bf16(ones, pf[nt], lacc[nt], 0, 0, 0);
#pragma unroll
            for (int dt = 0; dt < 4; ++dt)
#pragma unroll
                for (int nt = 0; nt < 2; ++nt)
                    oacc[nt][dt] = __builtin_amdgcn_mfma_f32_16x16x32_bf16(vf[dt], pf[nt], oacc[nt][dt], 0, 0, 0);
            __builtin_amdgcn_s_setprio(0);
        }
        barrier_vm0();   // prefetch drained; all waves done with KT/VT cur
    }

    // ---- epilogue: normalize, write bf16 [B,T,H*D]; O^T: col=q(l), row=d ----
#pragma unroll
    for (int nt = 0; nt < 2; ++nt) {
        const float inv = 1.0f / lacc[nt][0];
        const int t = q0 + w * 32 + nt * 16 + l;
#pragma unroll
        for (int dt = 0; dt < 4; ++dt) {
            uint2 p;
            p.x = pack_rne(oacc[nt][dt][0] * inv, oacc[nt][dt][1] * inv);
            p.y = pack_rne(oacc[nt][dt][2] * inv, oacc[nt][dt][3] * inv);
            *(uint2*)(Og + ((size_t)(b * Tn + t)) * INNERn + h * 64 + dt * 16 + quad * 4) = p;
        }
    }
}

// ---------------------------------------------------------------------------
extern "C" void kernel_launch(void* const* d_in, const int* in_sizes, int n_in,
                              void* d_out, int out_size, void* d_ws, size_t ws_size,
                              hipStream_t stream)
{
    const float* x  = (const float*)d_in[0];
    const float* Wk = (const float*)d_in[1];
    const float* Wq = (const float*)d_in[2];
    const float* Wv = (const float*)d_in[3];
    const float* Wp = (const float*)d_in[4];
    float* out = (float*)d_out;

    // workspace (all bf16): x | Wk | Wq | Wv | Wp | q | k | vT | ao
    ushort* xb  = (ushort*)d_ws;
    ushort* wkb = xb  + (size_t)Mn * Cn;
    ushort* wqb = wkb + (size_t)INNERn * Cn;
    ushort* wvb = wqb + (size_t)INNERn * Cn;
    ushort* wpb = wvb + (size_t)INNERn * Cn;
    ushort* qw  = wpb + (size_t)OUTn * INNERn;
    ushort* kw  = qw  + (size_t)Mn * INNERn;
    ushort* vtw = kw  + (size_t)Mn * INNERn;   // [B,H,D,T]
    ushort* aow = vtw + (size_t)Mn * INNERn;

    const dim3 blk(256);
    cvt_all<<<dim3(8192 + 4096), blk, 0, stream>>>(x, Wk, Wq, Wv, Wp,
                                                   xb, wkb, wqb, wvb, wpb);

    // q folds d^-0.5 * log2(e) so softmax runs in exp2 domain
    gemm_qkv<<<dim3(384), dim3(512), 0, stream>>>(xb, wqb, wkb, wvb,
                                                  qw, kw, vtw, 0.125f * 1.44269504f);

    attn_mfma<<<dim3(1024), blk, 0, stream>>>(qw, kw, vtw, aow);

    gemm_po<<<dim3(512), blk, 0, stream>>>(aow, wpb, out);
}